// Round 8
// baseline (1611.853 us; speedup 1.0000x reference)
//
#include <hip/hip_runtime.h>
#include <cstdint>

// Problem constants (fixed by the reference)
#define NN 4096
#define DD 1024
// TAU=0.8 -> 1/TAU = 1.25 ; INFONCE_TAU=0.1 -> *10 ; LAM=0.5 ; NUM_NEG=100

typedef __bf16 bf16x8 __attribute__((ext_vector_type(8)));
typedef float  f32x4  __attribute__((ext_vector_type(4)));
typedef unsigned short us8 __attribute__((ext_vector_type(8)));
typedef unsigned short us4 __attribute__((ext_vector_type(4)));

__device__ __forceinline__ unsigned short f2bf(float f) {
    unsigned int u = __float_as_uint(f);
    u += 0x7FFFu + ((u >> 16) & 1u);
    return (unsigned short)(u >> 16);
}
__device__ __forceinline__ float bf2f(unsigned short h) {
    return __uint_as_float(((unsigned int)h) << 16);
}

// ---------------------------------------------------------------------------
// prep: zero the accumulator region (32768 floats) + convert W1/W2 and all
// four z tensors to bf16 (Zall = [zmp1|zsc1|zmp2|zsc2], 16384x1024).
// ---------------------------------------------------------------------------
__global__ void prep(const float* __restrict__ zmp1, const float* __restrict__ zsc1,
                     const float* __restrict__ zmp2, const float* __restrict__ zsc2,
                     const float* __restrict__ W1, const float* __restrict__ W2,
                     unsigned short* __restrict__ Zall,
                     unsigned short* __restrict__ W1b, unsigned short* __restrict__ W2b,
                     float* __restrict__ zreg)
{
    const int i = blockIdx.x * 256 + threadIdx.x;   // 0 .. 1,048,575
    {
        float4 v = ((const float4*)zmp1)[i];
        us4 o; o.x=f2bf(v.x); o.y=f2bf(v.y); o.z=f2bf(v.z); o.w=f2bf(v.w);
        ((us4*)Zall)[i] = o;
        v = ((const float4*)zsc1)[i];
        o.x=f2bf(v.x); o.y=f2bf(v.y); o.z=f2bf(v.z); o.w=f2bf(v.w);
        ((us4*)(Zall + 4194304))[i] = o;
        v = ((const float4*)zmp2)[i];
        o.x=f2bf(v.x); o.y=f2bf(v.y); o.z=f2bf(v.z); o.w=f2bf(v.w);
        ((us4*)(Zall + 8388608))[i] = o;
        v = ((const float4*)zsc2)[i];
        o.x=f2bf(v.x); o.y=f2bf(v.y); o.z=f2bf(v.z); o.w=f2bf(v.w);
        ((us4*)(Zall + 12582912))[i] = o;
    }
    if (i < 524288) {
        const float4* src = (i < 262144) ? (const float4*)W1 : (const float4*)W2;
        us4* dst = (i < 262144) ? (us4*)W1b : (us4*)W2b;
        int k = i & 262143;
        float4 v = src[k];
        us4 o; o.x=f2bf(v.x); o.y=f2bf(v.y); o.z=f2bf(v.z); o.w=f2bf(v.w);
        dst[k] = o;
    }
    if (i < 8192) ((float4*)zreg)[i] = float4{0.f, 0.f, 0.f, 0.f};
}

// dual combine: z1 = bf16((1-g)a1 + g b1) ; z2 = bf16((1-g)a2 + g b2)
__global__ void combine2_bf16(const float* __restrict__ a1, const float* __restrict__ b1,
                              const float* __restrict__ a2, const float* __restrict__ b2,
                              const float* __restrict__ gamma,
                              unsigned short* __restrict__ z1, unsigned short* __restrict__ z2,
                              int n4each) {
    int i = blockIdx.x * 256 + threadIdx.x;
    float g = gamma[0];
    const float4 *sa, *sb; us4* dst; int k;
    if (i < n4each) { sa = (const float4*)a1; sb = (const float4*)b1; dst = (us4*)z1; k = i; }
    else { k = i - n4each; if (k >= n4each) return; sa = (const float4*)a2; sb = (const float4*)b2; dst = (us4*)z2; }
    float4 x = sa[k], y = sb[k];
    us4 o;
    o.x = f2bf((1.f - g) * x.x + g * y.x);
    o.y = f2bf((1.f - g) * x.y + g * y.y);
    o.z = f2bf((1.f - g) * x.z + g * y.z);
    o.w = f2bf((1.f - g) * x.w + g * y.w);
    dst[k] = o;
}

// ---------------------------------------------------------------------------
// GEMM-BT, LDS-free: C[r,c] = sum_k A[r,k]*B[c,k], A:[M,K], B:[N,K] bf16 rm.
// 128x128 block tile, 4 waves, 4x4 mfma_f32_16x16x32_bf16 per wave.
// Fragments are 16B-contiguous in global memory (A[row][q*8..+8]) and are
// loaded straight to VGPRs with global_load_dwordx4 — NO LDS, NO barriers,
// no vmcnt(0) drain. Register double-buffer (a0/b0 <-> a1/b1) keeps loads one
// iteration ahead; operand reuse is served by L1/L2/LLC.
// SWZ=1: XCD-aware decode for 32x32 grids (id&7 = XCD; concurrent q's share by;
//        each XCD's 4 B-slabs = 1 MB stay L2-resident).
// SWZ=0: bx = id % nbx, by = id / nbx (proj shape: B fits L2 everywhere).
// EPI 0: Out = bf16(elu(acc + bias[c]))
// EPI 1: Out = bf16(acc + bias[c]); nsqout[r] += (acc+bias)^2
// EPI 2: e = exp(acc/sqrt(nsq1[r])/sqrt(nsq2[c])*1.25); rowsum/colsum atomics; Out = bf16(e)
// EPI 3: Out = bf16(acc)
// ---------------------------------------------------------------------------
template<int EPI, int SWZ>
__global__ void gemm_bt(const unsigned short* __restrict__ A, const unsigned short* __restrict__ B,
                        int M, int N, int K, int nbx,
                        const float* __restrict__ bias, unsigned short* __restrict__ Out,
                        float* __restrict__ nsqout,
                        const float* __restrict__ nsq1, const float* __restrict__ nsq2,
                        float* __restrict__ rowsum, float* __restrict__ colsum)
{
    int bx, by;
    if constexpr (SWZ == 1) {
        const int id = blockIdx.x;          // 1024 blocks, 32x32 tiles
        const int x = id & 7, qq = id >> 3; // x = XCD (round-robin dispatch)
        bx = x * 4 + (qq & 3);
        by = qq >> 2;
    } else {
        bx = blockIdx.x % nbx;
        by = blockIdx.x / nbx;
    }
    const int tid  = threadIdx.x;
    const int wave = tid >> 6, lane = tid & 63;
    const int q = lane >> 4, l16 = lane & 15;
    const int m_base = by * 128, n_base = bx * 128;
    const int wm = (wave >> 1) * 64, wn = (wave & 1) * 64;

    f32x4 acc[4][4];
#pragma unroll
    for (int i = 0; i < 4; ++i)
#pragma unroll
        for (int j = 0; j < 4; ++j)
            acc[i][j] = f32x4{0.f, 0.f, 0.f, 0.f};

    // per-lane fragment base pointers (A-operand layout: A[m=l16][k=q*8+j])
    const unsigned short* Abase = A + (long)(m_base + wm + l16) * K + q * 8;
    const unsigned short* Bbase = B + (long)(n_base + wn + l16) * K + q * 8;
    const long rstride = (long)16 * K;

#define GEMM_LOAD(adst, bdst, koff)                                               \
    do {                                                                          \
        _Pragma("unroll")                                                         \
        for (int i = 0; i < 4; ++i) {                                             \
            adst[i] = *(const bf16x8*)(Abase + i * rstride + (koff));             \
            bdst[i] = *(const bf16x8*)(Bbase + i * rstride + (koff));             \
        }                                                                         \
    } while (0)

#define GEMM_COMPUTE(af, bfr)                                                     \
    do {                                                                          \
        _Pragma("unroll")                                                         \
        for (int i = 0; i < 4; ++i)                                               \
            _Pragma("unroll")                                                     \
            for (int j = 0; j < 4; ++j)                                           \
                acc[i][j] = __builtin_amdgcn_mfma_f32_16x16x32_bf16(af[i], bfr[j],\
                                                                    acc[i][j], 0, 0, 0); \
    } while (0)

    bf16x8 a0[4], b0[4], a1[4], b1[4];
    GEMM_LOAD(a0, b0, 0);
    const int nk = K >> 5;  // even (K = 1024)
    for (int k = 0; k < nk; k += 2) {
        if (k + 1 < nk) GEMM_LOAD(a1, b1, (k + 1) << 5);
        GEMM_COMPUTE(a0, b0);
        if (k + 2 < nk) GEMM_LOAD(a0, b0, (k + 2) << 5);
        GEMM_COMPUTE(a1, b1);
    }
#undef GEMM_LOAD
#undef GEMM_COMPUTE

    // C/D layout: row = q*4 + reg, col = l16
    const int r_base = m_base + wm + q * 4;
    const int c_base = n_base + wn + l16;

    if constexpr (EPI == 0 || EPI == 1) {
        float sq[4][4] = {};
#pragma unroll
        for (int j = 0; j < 4; ++j) {
            const int col = c_base + j * 16;
            const float bv = bias[col];
#pragma unroll
            for (int i = 0; i < 4; ++i)
#pragma unroll
                for (int r = 0; r < 4; ++r) {
                    const int row = r_base + i * 16 + r;
                    float v = acc[i][j][r] + bv;
                    if constexpr (EPI == 0) v = v > 0.f ? v : expm1f(v);
                    if constexpr (EPI == 1) sq[i][r] += v * v;
                    Out[(long)row * N + col] = f2bf(v);
                }
        }
        if constexpr (EPI == 1) {
#pragma unroll
            for (int m = 1; m < 16; m <<= 1)
#pragma unroll
                for (int i = 0; i < 4; ++i)
#pragma unroll
                    for (int r = 0; r < 4; ++r)
                        sq[i][r] += __shfl_xor(sq[i][r], m);
            if (l16 == 0)
#pragma unroll
                for (int i = 0; i < 4; ++i)
#pragma unroll
                    for (int r = 0; r < 4; ++r)
                        atomicAdd(&nsqout[r_base + i * 16 + r], sq[i][r]);
        }
    } else if constexpr (EPI == 2) {
        float i1[4][4], i2[4];
#pragma unroll
        for (int i = 0; i < 4; ++i)
#pragma unroll
            for (int r = 0; r < 4; ++r)
                i1[i][r] = 1.f / sqrtf(nsq1[r_base + i * 16 + r]);
#pragma unroll
        for (int j = 0; j < 4; ++j) i2[j] = 1.f / sqrtf(nsq2[c_base + j * 16]);
        float rs[4][4] = {};
        float cs[4] = {};
#pragma unroll
        for (int i = 0; i < 4; ++i)
#pragma unroll
            for (int j = 0; j < 4; ++j)
#pragma unroll
                for (int r = 0; r < 4; ++r) {
                    float e = expf(acc[i][j][r] * i1[i][r] * i2[j] * 1.25f);
                    rs[i][r] += e;
                    cs[j] += e;
                    Out[(long)(r_base + i * 16 + r) * N + (c_base + j * 16)] = f2bf(e);
                }
#pragma unroll
        for (int m = 1; m < 16; m <<= 1)
#pragma unroll
            for (int i = 0; i < 4; ++i)
#pragma unroll
                for (int r = 0; r < 4; ++r)
                    rs[i][r] += __shfl_xor(rs[i][r], m);
        if (l16 == 0)
#pragma unroll
            for (int i = 0; i < 4; ++i)
#pragma unroll
                for (int r = 0; r < 4; ++r)
                    atomicAdd(&rowsum[r_base + i * 16 + r], rs[i][r]);
#pragma unroll
        for (int m = 16; m < 64; m <<= 1)
#pragma unroll
            for (int j = 0; j < 4; ++j)
                cs[j] += __shfl_xor(cs[j], m);
        if (q == 0)
#pragma unroll
            for (int j = 0; j < 4; ++j)
                atomicAdd(&colsum[c_base + j * 16], cs[j]);
    } else {  // EPI == 3
#pragma unroll
        for (int j = 0; j < 4; ++j)
#pragma unroll
            for (int i = 0; i < 4; ++i)
#pragma unroll
                for (int r = 0; r < 4; ++r)
                    Out[(long)(r_base + i * 16 + r) * N + (c_base + j * 16)] = f2bf(acc[i][j][r]);
    }
}

// One wave per row i: mr[i] = sum_{pos[i,j]>0} S[i,j]; mc[i] = sum_{pos[i,j]>0} S[j,i].
__global__ void pos_row(const float* __restrict__ pos, const unsigned short* __restrict__ S,
                        float* __restrict__ mr, float* __restrict__ mc)
{
    const int row = (blockIdx.x * blockDim.x + threadIdx.x) >> 6;
    const int lane = threadIdx.x & 63;
    if (row >= NN) return;
    const float* prow = pos + (long)row * NN;
    const unsigned short* srow = S + (long)row * NN;
    float e1 = 0.f, e2 = 0.f;
    for (int b = 0; b < NN; b += 256) {
        float4 v = *(const float4*)(prow + b + lane * 4);
#pragma unroll
        for (int t = 0; t < 4; ++t) {
            float pv = (&v.x)[t];
            if (pv != 0.f) {
                int j = b + lane * 4 + t;
                e1 += bf2f(srow[j]);
                e2 += bf2f(S[(long)j * NN + row]);
            }
        }
    }
#pragma unroll
    for (int m = 1; m < 64; m <<= 1) { e1 += __shfl_xor(e1, m); e2 += __shfl_xor(e2, m); }
    if (lane == 0) { mr[row] = e1; mc[row] = e2; }
}

// One wave per row: lse over first-100 md==0 cols (ballot+prefix-rank), then md>0 terms.
__global__ void md_row(const float* __restrict__ md, const unsigned short* __restrict__ S,
                       float* __restrict__ wsum, float* __restrict__ wcnt)
{
    const int row = (blockIdx.x * blockDim.x + threadIdx.x) >> 6;
    const int lane = threadIdx.x & 63;
    if (row >= NN) return;
    const float* mrow = md + (long)row * NN;
    const unsigned short* srow = S + (long)row * NN;

    const unsigned long long below = (1ull << lane) - 1ull;
    float se = 0.f;
    int found = 0;
    for (int b = 0; b < NN && found < 100; b += 64) {
        float v = mrow[b + lane];
        unsigned long long zm = __ballot(v == 0.f);
        int rank = found + __popcll(zm & below);
        if (v == 0.f && rank < 100)
            se += expf(bf2f(srow[b + lane]) * 10.f);
        found += __popcll(zm);
    }
#pragma unroll
    for (int m = 1; m < 64; m <<= 1) se += __shfl_xor(se, m);
    const float L = logf(se);

    float ws = 0.f, wc = 0.f;
    for (int b = 0; b < NN; b += 256) {
        float4 v = *(const float4*)(mrow + b + lane * 4);
#pragma unroll
        for (int t = 0; t < 4; ++t) {
            float mv = (&v.x)[t];
            if (mv != 0.f) {
                float p = bf2f(srow[b + lane * 4 + t]) * 10.f;
                ws += (fmaxf(p, L) - p) + log1pf(expf(-fabsf(p - L)));
                wc += 1.f;
            }
        }
    }
#pragma unroll
    for (int m = 1; m < 64; m <<= 1) { ws += __shfl_xor(ws, m); wc += __shfl_xor(wc, m); }
    if (lane == 0) { wsum[row] = ws; wcnt[row] = wc; }
}

__global__ void finalize(const float* __restrict__ rs1, const float* __restrict__ cs1,
                         const float* __restrict__ mr1, const float* __restrict__ mc1,
                         const float* __restrict__ rs2, const float* __restrict__ cs2,
                         const float* __restrict__ mr2, const float* __restrict__ mc2,
                         const float* __restrict__ wsum, const float* __restrict__ wcnt,
                         unsigned int* __restrict__ out)
{
    __shared__ float redt[256], reds[256], redc[256];
    const int tid = threadIdx.x;
    float t = 0.f, s = 0.f, c = 0.f;
    for (int i = tid; i < NN; i += 256) {
        t -= logf(mr1[i] / (rs1[i] + 1e-8f));
        t -= logf(mc1[i] / (cs1[i] + 1e-8f));
        t -= logf(mr2[i] / (rs2[i] + 1e-8f));
        t -= logf(mc2[i] / (cs2[i] + 1e-8f));
        s += wsum[i];
        c += wcnt[i];
    }
    redt[tid] = t; reds[tid] = s; redc[tid] = c;
    __syncthreads();
    for (int st = 128; st > 0; st >>= 1) {
        if (tid < st) { redt[tid] += redt[tid + st]; reds[tid] += reds[tid + st]; redc[tid] += redc[tid + st]; }
        __syncthreads();
    }
    if (tid == 0) {
        float loss = 0.5f * redt[0] / (float)NN + reds[0] / redc[0];
        unsigned int bf = (unsigned int)f2bf(loss);
        out[0] = bf | (bf << 16);
    }
}

extern "C" void kernel_launch(void* const* d_in, const int* in_sizes, int n_in,
                              void* d_out, int out_size, void* d_ws, size_t ws_size,
                              hipStream_t stream) {
    const float* z_mp1 = (const float*)d_in[0];
    const float* z_sc1 = (const float*)d_in[1];
    const float* pos1  = (const float*)d_in[2];
    const float* z_mp2 = (const float*)d_in[3];
    const float* z_sc2 = (const float*)d_in[4];
    const float* pos2  = (const float*)d_in[5];
    const float* mdm   = (const float*)d_in[6];
    const float* gamma = (const float*)d_in[7];
    const float* W1    = (const float*)d_in[8];
    const float* b1    = (const float*)d_in[9];
    const float* W2    = (const float*)d_in[10];
    const float* b2    = (const float*)d_in[11];

    char* ws = (char*)d_ws;
    unsigned short* W1b = (unsigned short*)ws;                          // 0..2 MB
    unsigned short* W2b = (unsigned short*)(ws + (size_t)(2u << 20));   // 2..4 MB
    unsigned short* Zall = (unsigned short*)(ws + (size_t)(4u << 20));  // 4..36 MB

    const bool big = ws_size >= ((size_t)70 << 20);

    if (big) {
        // ---- merged layout (peak ~68.3 MB), race-free S ----
        unsigned short* Hall = (unsigned short*)(ws + (size_t)(36u << 20));
        unsigned short* Pall = Zall;
        unsigned short* Sbf  = Hall;
        unsigned short* Z1b  = Zall;
        unsigned short* Z2b  = Zall + 8388608;
        float* acc = (float*)(ws + (size_t)(68u << 20));
        float* nsq  = acc;            // 16384: [mp1|sc1|mp2|sc2]
        float* rs1  = acc + 16384;
        float* cs1  = rs1 + 4096;
        float* rs2  = cs1 + 4096;
        float* cs2  = rs2 + 4096;
        float* mr1  = cs2 + 4096;
        float* mc1  = mr1 + 4096;
        float* mr2  = mc1 + 4096;
        float* mc2  = mr2 + 4096;
        float* wsum = mc2 + 4096;
        float* wcnt = wsum + 4096;

        prep<<<dim3(4096), dim3(256), 0, stream>>>(z_mp1, z_sc1, z_mp2, z_sc2, W1, W2,
                                                   Zall, W1b, W2b, acc);
        gemm_bt<0, 0><<<dim3(1024), dim3(256), 0, stream>>>(Zall, W1b, 16384, 1024, 1024, 8,
            b1, Hall, nullptr, nullptr, nullptr, nullptr, nullptr);
        gemm_bt<1, 0><<<dim3(1024), dim3(256), 0, stream>>>(Hall, W2b, 16384, 1024, 1024, 8,
            b2, Pall, nsq, nullptr, nullptr, nullptr, nullptr);
        gemm_bt<2, 1><<<dim3(1024), dim3(256), 0, stream>>>(Pall, Pall + 4194304, 4096, 4096, 1024, 32,
            nullptr, Sbf, nullptr, nsq, nsq + 4096, rs1, cs1);
        pos_row<<<dim3(1024), dim3(256), 0, stream>>>(pos1, Sbf, mr1, mc1);
        gemm_bt<2, 1><<<dim3(1024), dim3(256), 0, stream>>>(Pall + 8388608, Pall + 12582912, 4096, 4096, 1024, 32,
            nullptr, Sbf, nullptr, nsq + 8192, nsq + 12288, rs2, cs2);
        pos_row<<<dim3(1024), dim3(256), 0, stream>>>(pos2, Sbf, mr2, mc2);
        combine2_bf16<<<dim3(8192), dim3(256), 0, stream>>>(z_mp1, z_sc1, z_mp2, z_sc2, gamma,
                                                            Z1b, Z2b, 1048576);
        gemm_bt<3, 1><<<dim3(1024), dim3(256), 0, stream>>>(Z1b, Z2b, 4096, 4096, 1024, 32,
            nullptr, Sbf, nullptr, nullptr, nullptr, nullptr, nullptr);
        md_row<<<dim3(1024), dim3(256), 0, stream>>>(mdm, Sbf, wsum, wcnt);
        finalize<<<dim3(1), dim3(256), 0, stream>>>(rs1, cs1, mr1, mc1, rs2, cs2, mr2, mc2,
                                                    wsum, wcnt, (unsigned int*)d_out);
    } else {
        // ---- split fallback (peak ~52.4 MB) ----
        unsigned short* Pv1 = (unsigned short*)(ws + (size_t)(4u << 20));
        unsigned short* Pv2 = (unsigned short*)(ws + (size_t)(20u << 20));
        unsigned short* Sbf = (unsigned short*)(ws + (size_t)(4u << 20));
        unsigned short* HBf = (unsigned short*)(ws + (size_t)(36u << 20));
        unsigned short* Z1b = (unsigned short*)(ws + (size_t)(36u << 20));
        unsigned short* Z2b = (unsigned short*)(ws + (size_t)(44u << 20));
        float* acc = (float*)(ws + (size_t)(52u << 20));
        float* nsq  = acc;            // 16384: [v1 mp|sc | v2 mp|sc]
        float* rs1  = acc + 16384;
        float* cs1  = rs1 + 4096;
        float* rs2  = cs1 + 4096;
        float* cs2  = rs2 + 4096;
        float* mr1  = cs2 + 4096;
        float* mc1  = mr1 + 4096;
        float* mr2  = mc1 + 4096;
        float* mc2  = mr2 + 4096;
        float* wsum = mc2 + 4096;
        float* wcnt = wsum + 4096;

        prep<<<dim3(4096), dim3(256), 0, stream>>>(z_mp1, z_sc1, z_mp2, z_sc2, W1, W2,
                                                   Zall, W1b, W2b, acc);
        gemm_bt<0, 0><<<dim3(512), dim3(256), 0, stream>>>(Zall, W1b, 8192, 1024, 1024, 8,
            b1, HBf, nullptr, nullptr, nullptr, nullptr, nullptr);
        gemm_bt<1, 0><<<dim3(512), dim3(256), 0, stream>>>(HBf, W2b, 8192, 1024, 1024, 8,
            b2, Pv1, nsq, nullptr, nullptr, nullptr, nullptr);
        gemm_bt<2, 1><<<dim3(1024), dim3(256), 0, stream>>>(Pv1, Pv1 + 4194304, 4096, 4096, 1024, 32,
            nullptr, Sbf, nullptr, nsq, nsq + 4096, rs1, cs1);
        pos_row<<<dim3(1024), dim3(256), 0, stream>>>(pos1, Sbf, mr1, mc1);
        gemm_bt<0, 0><<<dim3(512), dim3(256), 0, stream>>>(Zall + 8388608, W1b, 8192, 1024, 1024, 8,
            b1, HBf, nullptr, nullptr, nullptr, nullptr, nullptr);
        gemm_bt<1, 0><<<dim3(512), dim3(256), 0, stream>>>(HBf, W2b, 8192, 1024, 1024, 8,
            b2, Pv2, nsq + 8192, nullptr, nullptr, nullptr, nullptr);
        gemm_bt<2, 1><<<dim3(1024), dim3(256), 0, stream>>>(Pv2, Pv2 + 4194304, 4096, 4096, 1024, 32,
            nullptr, Sbf, nullptr, nsq + 8192, nsq + 12288, rs2, cs2);
        pos_row<<<dim3(1024), dim3(256), 0, stream>>>(pos2, Sbf, mr2, mc2);
        combine2_bf16<<<dim3(8192), dim3(256), 0, stream>>>(z_mp1, z_sc1, z_mp2, z_sc2, gamma,
                                                            Z1b, Z2b, 1048576);
        gemm_bt<3, 1><<<dim3(1024), dim3(256), 0, stream>>>(Z1b, Z2b, 4096, 4096, 1024, 32,
            nullptr, Sbf, nullptr, nullptr, nullptr, nullptr, nullptr);
        md_row<<<dim3(1024), dim3(256), 0, stream>>>(mdm, Sbf, wsum, wcnt);
        finalize<<<dim3(1), dim3(256), 0, stream>>>(rs1, cs1, mr1, mc1, rs2, cs2, mr2, mc2,
                                                    wsum, wcnt, (unsigned int*)d_out);
    }
}

// Round 9
// 580.571 us; speedup vs baseline: 2.7763x; 2.7763x over previous
//
#include <hip/hip_runtime.h>
#include <cstdint>

// Problem constants (fixed by the reference)
#define NN 4096
#define DD 1024
// TAU=0.8 -> 1/TAU = 1.25 ; INFONCE_TAU=0.1 -> *10 ; LAM=0.5 ; NUM_NEG=100

typedef __bf16 bf16x8 __attribute__((ext_vector_type(8)));
typedef float  f32x4  __attribute__((ext_vector_type(4)));
typedef unsigned short us8 __attribute__((ext_vector_type(8)));
typedef unsigned short us4 __attribute__((ext_vector_type(4)));

__device__ __forceinline__ unsigned short f2bf(float f) {
    unsigned int u = __float_as_uint(f);
    u += 0x7FFFu + ((u >> 16) & 1u);
    return (unsigned short)(u >> 16);
}
__device__ __forceinline__ float bf2f(unsigned short h) {
    return __uint_as_float(((unsigned int)h) << 16);
}

// async global->LDS, 16B per lane. LDS dest is wave-uniform base; HW adds lane*16.
typedef const void __attribute__((address_space(1)))* gvp;
typedef void __attribute__((address_space(3)))* svp;
__device__ __forceinline__ void async_copy16(const void* g, void* l) {
    __builtin_amdgcn_global_load_lds((gvp)(uintptr_t)g, (svp)(uint32_t)(uintptr_t)l, 16, 0, 0);
}

// ---------------------------------------------------------------------------
// prep: zero the accumulator region (32768 floats) + convert W1/W2 and all
// four z tensors to bf16 (Zall = [zmp1|zsc1|zmp2|zsc2], 16384x1024).
// ---------------------------------------------------------------------------
__global__ void prep(const float* __restrict__ zmp1, const float* __restrict__ zsc1,
                     const float* __restrict__ zmp2, const float* __restrict__ zsc2,
                     const float* __restrict__ W1, const float* __restrict__ W2,
                     unsigned short* __restrict__ Zall,
                     unsigned short* __restrict__ W1b, unsigned short* __restrict__ W2b,
                     float* __restrict__ zreg)
{
    const int i = blockIdx.x * 256 + threadIdx.x;   // 0 .. 1,048,575
    {
        float4 v = ((const float4*)zmp1)[i];
        us4 o; o.x=f2bf(v.x); o.y=f2bf(v.y); o.z=f2bf(v.z); o.w=f2bf(v.w);
        ((us4*)Zall)[i] = o;
        v = ((const float4*)zsc1)[i];
        o.x=f2bf(v.x); o.y=f2bf(v.y); o.z=f2bf(v.z); o.w=f2bf(v.w);
        ((us4*)(Zall + 4194304))[i] = o;
        v = ((const float4*)zmp2)[i];
        o.x=f2bf(v.x); o.y=f2bf(v.y); o.z=f2bf(v.z); o.w=f2bf(v.w);
        ((us4*)(Zall + 8388608))[i] = o;
        v = ((const float4*)zsc2)[i];
        o.x=f2bf(v.x); o.y=f2bf(v.y); o.z=f2bf(v.z); o.w=f2bf(v.w);
        ((us4*)(Zall + 12582912))[i] = o;
    }
    if (i < 524288) {
        const float4* src = (i < 262144) ? (const float4*)W1 : (const float4*)W2;
        us4* dst = (i < 262144) ? (us4*)W1b : (us4*)W2b;
        int k = i & 262143;
        float4 v = src[k];
        us4 o; o.x=f2bf(v.x); o.y=f2bf(v.y); o.z=f2bf(v.z); o.w=f2bf(v.w);
        dst[k] = o;
    }
    if (i < 8192) ((float4*)zreg)[i] = float4{0.f, 0.f, 0.f, 0.f};
}

// dual combine: z1 = bf16((1-g)a1 + g b1) ; z2 = bf16((1-g)a2 + g b2)
__global__ void combine2_bf16(const float* __restrict__ a1, const float* __restrict__ b1,
                              const float* __restrict__ a2, const float* __restrict__ b2,
                              const float* __restrict__ gamma,
                              unsigned short* __restrict__ z1, unsigned short* __restrict__ z2,
                              int n4each) {
    int i = blockIdx.x * 256 + threadIdx.x;
    float g = gamma[0];
    const float4 *sa, *sb; us4* dst; int k;
    if (i < n4each) { sa = (const float4*)a1; sb = (const float4*)b1; dst = (us4*)z1; k = i; }
    else { k = i - n4each; if (k >= n4each) return; sa = (const float4*)a2; sb = (const float4*)b2; dst = (us4*)z2; }
    float4 x = sa[k], y = sb[k];
    us4 o;
    o.x = f2bf((1.f - g) * x.x + g * y.x);
    o.y = f2bf((1.f - g) * x.y + g * y.y);
    o.z = f2bf((1.f - g) * x.z + g * y.z);
    o.w = f2bf((1.f - g) * x.w + g * y.w);
    dst[k] = o;
}

// ---------------------------------------------------------------------------
// GEMM-BT (R7-proven): C[r,c] = sum_k A[r,k]*B[c,k], A:[M,K], B:[N,K] bf16 rm.
// 128x128 tile, BK=32, 4 waves, 4x4 mfma_f32_16x16x32_bf16 per wave.
// Single-barrier pipelined double-buffer K-loop, unrolled x2.
// EPI 0: Out = bf16(elu(acc + bias[c]))
// EPI 1: Out = bf16(acc + bias[c]); nsqout[r] += (acc+bias)^2
// EPI 2: e = exp(acc/sqrt(nsq1[r])/sqrt(nsq2[c])*1.25); rowsum/colsum atomics; Out = bf16(e)
// EPI 3: Out = bf16(acc)
// ---------------------------------------------------------------------------
template<int EPI>
__global__ void gemm_bt(const unsigned short* __restrict__ A, const unsigned short* __restrict__ B,
                        int M, int N, int K,
                        const float* __restrict__ bias, unsigned short* __restrict__ Out,
                        float* __restrict__ nsqout,
                        const float* __restrict__ nsq1, const float* __restrict__ nsq2,
                        float* __restrict__ rowsum, float* __restrict__ colsum)
{
    __shared__ alignas(16) unsigned short As0[128 * 32], As1[128 * 32];
    __shared__ alignas(16) unsigned short Bs0[128 * 32], Bs1[128 * 32];
    const int tid  = threadIdx.x;
    const int wave = tid >> 6, lane = tid & 63;
    const int q = lane >> 4, l16 = lane & 15;
    const int m_base = blockIdx.y * 128, n_base = blockIdx.x * 128;
    const int wm = (wave >> 1) * 64, wn = (wave & 1) * 64;

    f32x4 acc[4][4];
#pragma unroll
    for (int i = 0; i < 4; ++i)
#pragma unroll
        for (int j = 0; j < 4; ++j)
            acc[i][j] = f32x4{0.f, 0.f, 0.f, 0.f};

    const int ld_row = wave * 32 + (lane >> 2);
    const int ld_col = (lane & 3) * 8;
    const unsigned short* Ag0 = A + (long)(m_base + ld_row) * K + ld_col;
    const unsigned short* Ag1 = Ag0 + 16 * (long)K;
    const unsigned short* Bg0 = B + (long)(n_base + ld_row) * K + ld_col;
    const unsigned short* Bg1 = Bg0 + 16 * (long)K;
    const int lds_off = wave * 1024;

#define GEMM_STAGE(ASB, BSB, koff)                          \
    do {                                                    \
        async_copy16(Ag0 + (koff), (ASB) + lds_off);        \
        async_copy16(Ag1 + (koff), (ASB) + lds_off + 512);  \
        async_copy16(Bg0 + (koff), (BSB) + lds_off);        \
        async_copy16(Bg1 + (koff), (BSB) + lds_off + 512);  \
    } while (0)

#define GEMM_COMPUTE(ASB, BSB)                                                        \
    do {                                                                              \
        bf16x8 af[4], bfr[4];                                                         \
        _Pragma("unroll")                                                             \
        for (int i = 0; i < 4; ++i)                                                   \
            af[i] = *(const bf16x8*)((ASB) + (wm + i * 16 + l16) * 32 + q * 8);       \
        _Pragma("unroll")                                                             \
        for (int j = 0; j < 4; ++j)                                                   \
            bfr[j] = *(const bf16x8*)((BSB) + (wn + j * 16 + l16) * 32 + q * 8);      \
        _Pragma("unroll")                                                             \
        for (int i = 0; i < 4; ++i)                                                   \
            _Pragma("unroll")                                                         \
            for (int j = 0; j < 4; ++j)                                               \
                acc[i][j] = __builtin_amdgcn_mfma_f32_16x16x32_bf16(af[i], bfr[j],    \
                                                                    acc[i][j], 0, 0, 0); \
    } while (0)

    GEMM_STAGE(As0, Bs0, 0);

    const int nk = K >> 5;  // even (K = 1024)
    for (int k = 0; k < nk; k += 2) {
        __syncthreads();
        if (k + 1 < nk) GEMM_STAGE(As1, Bs1, (k + 1) << 5);
        GEMM_COMPUTE(As0, Bs0);
        __syncthreads();
        if (k + 2 < nk) GEMM_STAGE(As0, Bs0, (k + 2) << 5);
        GEMM_COMPUTE(As1, Bs1);
    }
#undef GEMM_STAGE
#undef GEMM_COMPUTE

    // C/D layout: row = q*4 + reg, col = l16
    const int r_base = m_base + wm + q * 4;
    const int c_base = n_base + wn + l16;

    if constexpr (EPI == 0 || EPI == 1) {
        float sq[4][4] = {};
#pragma unroll
        for (int j = 0; j < 4; ++j) {
            const int col = c_base + j * 16;
            const float bv = bias[col];
#pragma unroll
            for (int i = 0; i < 4; ++i)
#pragma unroll
                for (int r = 0; r < 4; ++r) {
                    const int row = r_base + i * 16 + r;
                    float v = acc[i][j][r] + bv;
                    if constexpr (EPI == 0) v = v > 0.f ? v : expm1f(v);
                    if constexpr (EPI == 1) sq[i][r] += v * v;
                    Out[(long)row * N + col] = f2bf(v);
                }
        }
        if constexpr (EPI == 1) {
#pragma unroll
            for (int m = 1; m < 16; m <<= 1)
#pragma unroll
                for (int i = 0; i < 4; ++i)
#pragma unroll
                    for (int r = 0; r < 4; ++r)
                        sq[i][r] += __shfl_xor(sq[i][r], m);
            if (l16 == 0)
#pragma unroll
                for (int i = 0; i < 4; ++i)
#pragma unroll
                    for (int r = 0; r < 4; ++r)
                        atomicAdd(&nsqout[r_base + i * 16 + r], sq[i][r]);
        }
    } else if constexpr (EPI == 2) {
        float i1[4][4], i2[4];
#pragma unroll
        for (int i = 0; i < 4; ++i)
#pragma unroll
            for (int r = 0; r < 4; ++r)
                i1[i][r] = 1.f / sqrtf(nsq1[r_base + i * 16 + r]);
#pragma unroll
        for (int j = 0; j < 4; ++j) i2[j] = 1.f / sqrtf(nsq2[c_base + j * 16]);
        float rs[4][4] = {};
        float cs[4] = {};
#pragma unroll
        for (int i = 0; i < 4; ++i)
#pragma unroll
            for (int j = 0; j < 4; ++j)
#pragma unroll
                for (int r = 0; r < 4; ++r) {
                    float e = expf(acc[i][j][r] * i1[i][r] * i2[j] * 1.25f);
                    rs[i][r] += e;
                    cs[j] += e;
                    Out[(long)(r_base + i * 16 + r) * N + (c_base + j * 16)] = f2bf(e);
                }
#pragma unroll
        for (int m = 1; m < 16; m <<= 1)
#pragma unroll
            for (int i = 0; i < 4; ++i)
#pragma unroll
                for (int r = 0; r < 4; ++r)
                    rs[i][r] += __shfl_xor(rs[i][r], m);
        if (l16 == 0)
#pragma unroll
            for (int i = 0; i < 4; ++i)
#pragma unroll
                for (int r = 0; r < 4; ++r)
                    atomicAdd(&rowsum[r_base + i * 16 + r], rs[i][r]);
#pragma unroll
        for (int m = 16; m < 64; m <<= 1)
#pragma unroll
            for (int j = 0; j < 4; ++j)
                cs[j] += __shfl_xor(cs[j], m);
        if (q == 0)
#pragma unroll
            for (int j = 0; j < 4; ++j)
                atomicAdd(&colsum[c_base + j * 16], cs[j]);
    } else {  // EPI == 3
#pragma unroll
        for (int j = 0; j < 4; ++j)
#pragma unroll
            for (int i = 0; i < 4; ++i)
#pragma unroll
                for (int r = 0; r < 4; ++r)
                    Out[(long)(r_base + i * 16 + r) * N + (c_base + j * 16)] = f2bf(acc[i][j][r]);
    }
}

// Block-per-row (4 waves split the 4096 columns): mr[row] = sum_{pos[row,j]>0} S[row,j];
// mc[row] = sum_{pos[row,j]>0} S[j,row]. 4x the wave-parallelism of wave-per-row.
__global__ void pos_row(const float* __restrict__ pos, const unsigned short* __restrict__ S,
                        float* __restrict__ mr, float* __restrict__ mc)
{
    const int row = blockIdx.x;
    const int tid = threadIdx.x, wave = tid >> 6, lane = tid & 63;
    const float* prow = pos + (long)row * NN;
    const unsigned short* srow = S + (long)row * NN;
    float e1 = 0.f, e2 = 0.f;
    const int base = wave * 1024 + lane * 4;   // wave covers a 1024-col quarter
#pragma unroll
    for (int it = 0; it < 4; ++it) {
        float4 v = *(const float4*)(prow + base + it * 256);
#pragma unroll
        for (int t = 0; t < 4; ++t) {
            float pv = (&v.x)[t];
            if (pv != 0.f) {
                int j = base + it * 256 + t;
                e1 += bf2f(srow[j]);
                e2 += bf2f(S[(long)j * NN + row]);
            }
        }
    }
#pragma unroll
    for (int m = 1; m < 64; m <<= 1) { e1 += __shfl_xor(e1, m); e2 += __shfl_xor(e2, m); }
    __shared__ float r1[4], r2[4];
    if (lane == 0) { r1[wave] = e1; r2[wave] = e2; }
    __syncthreads();
    if (tid == 0) {
        mr[row] = r1[0] + r1[1] + r1[2] + r1[3];
        mc[row] = r2[0] + r2[1] + r2[2] + r2[3];
    }
}

// Block-per-row: phase 1 (first-100 md==0 lse) computed redundantly by all 4 waves
// (touches only the first ~128 cols — L1-resident); phase 2 (md>0 terms) split
// across waves by column quarter.
__global__ void md_row(const float* __restrict__ md, const unsigned short* __restrict__ S,
                       float* __restrict__ wsum, float* __restrict__ wcnt)
{
    const int row = blockIdx.x;
    const int tid = threadIdx.x, wave = tid >> 6, lane = tid & 63;
    const float* mrow = md + (long)row * NN;
    const unsigned short* srow = S + (long)row * NN;

    // Phase 1: first-100 md==0 columns via ballot + prefix rank (per-wave, identical)
    const unsigned long long below = (1ull << lane) - 1ull;
    float se = 0.f;
    int found = 0;
    for (int b = 0; b < NN && found < 100; b += 64) {
        float v = mrow[b + lane];
        unsigned long long zm = __ballot(v == 0.f);
        int rank = found + __popcll(zm & below);
        if (v == 0.f && rank < 100)
            se += expf(bf2f(srow[b + lane]) * 10.f);
        found += __popcll(zm);
    }
#pragma unroll
    for (int m = 1; m < 64; m <<= 1) se += __shfl_xor(se, m);
    const float L = logf(se);

    // Phase 2: md>0 terms, column quarter per wave
    float ws = 0.f, wc = 0.f;
    const int base = wave * 1024 + lane * 4;
#pragma unroll
    for (int it = 0; it < 4; ++it) {
        float4 v = *(const float4*)(mrow + base + it * 256);
#pragma unroll
        for (int t = 0; t < 4; ++t) {
            float mv = (&v.x)[t];
            if (mv != 0.f) {
                float p = bf2f(srow[base + it * 256 + t]) * 10.f;
                ws += (fmaxf(p, L) - p) + log1pf(expf(-fabsf(p - L)));
                wc += 1.f;
            }
        }
    }
#pragma unroll
    for (int m = 1; m < 64; m <<= 1) { ws += __shfl_xor(ws, m); wc += __shfl_xor(wc, m); }
    __shared__ float r1[4], r2[4];
    if (lane == 0) { r1[wave] = ws; r2[wave] = wc; }
    __syncthreads();
    if (tid == 0) {
        wsum[row] = r1[0] + r1[1] + r1[2] + r1[3];
        wcnt[row] = r2[0] + r2[1] + r2[2] + r2[3];
    }
}

__global__ void finalize(const float* __restrict__ rs1, const float* __restrict__ cs1,
                         const float* __restrict__ mr1, const float* __restrict__ mc1,
                         const float* __restrict__ rs2, const float* __restrict__ cs2,
                         const float* __restrict__ mr2, const float* __restrict__ mc2,
                         const float* __restrict__ wsum, const float* __restrict__ wcnt,
                         unsigned int* __restrict__ out)
{
    __shared__ float redt[256], reds[256], redc[256];
    const int tid = threadIdx.x;
    float t = 0.f, s = 0.f, c = 0.f;
    for (int i = tid; i < NN; i += 256) {
        t -= logf(mr1[i] / (rs1[i] + 1e-8f));
        t -= logf(mc1[i] / (cs1[i] + 1e-8f));
        t -= logf(mr2[i] / (rs2[i] + 1e-8f));
        t -= logf(mc2[i] / (cs2[i] + 1e-8f));
        s += wsum[i];
        c += wcnt[i];
    }
    redt[tid] = t; reds[tid] = s; redc[tid] = c;
    __syncthreads();
    for (int st = 128; st > 0; st >>= 1) {
        if (tid < st) { redt[tid] += redt[tid + st]; reds[tid] += reds[tid + st]; redc[tid] += redc[tid + st]; }
        __syncthreads();
    }
    if (tid == 0) {
        float loss = 0.5f * redt[0] / (float)NN + reds[0] / redc[0];
        unsigned int bf = (unsigned int)f2bf(loss);
        out[0] = bf | (bf << 16);
    }
}

extern "C" void kernel_launch(void* const* d_in, const int* in_sizes, int n_in,
                              void* d_out, int out_size, void* d_ws, size_t ws_size,
                              hipStream_t stream) {
    const float* z_mp1 = (const float*)d_in[0];
    const float* z_sc1 = (const float*)d_in[1];
    const float* pos1  = (const float*)d_in[2];
    const float* z_mp2 = (const float*)d_in[3];
    const float* z_sc2 = (const float*)d_in[4];
    const float* pos2  = (const float*)d_in[5];
    const float* mdm   = (const float*)d_in[6];
    const float* gamma = (const float*)d_in[7];
    const float* W1    = (const float*)d_in[8];
    const float* b1    = (const float*)d_in[9];
    const float* W2    = (const float*)d_in[10];
    const float* b2    = (const float*)d_in[11];

    char* ws = (char*)d_ws;
    unsigned short* W1b = (unsigned short*)ws;                          // 0..2 MB
    unsigned short* W2b = (unsigned short*)(ws + (size_t)(2u << 20));   // 2..4 MB
    unsigned short* Zall = (unsigned short*)(ws + (size_t)(4u << 20));  // 4..36 MB

    const bool big = ws_size >= ((size_t)70 << 20);

    if (big) {
        // ---- merged layout (peak ~68.3 MB), race-free S ----
        unsigned short* Hall = (unsigned short*)(ws + (size_t)(36u << 20));
        unsigned short* Pall = Zall;
        unsigned short* Sbf  = Hall;
        unsigned short* Z1b  = Zall;
        unsigned short* Z2b  = Zall + 8388608;
        float* acc = (float*)(ws + (size_t)(68u << 20));
        float* nsq  = acc;            // 16384: [mp1|sc1|mp2|sc2]
        float* rs1  = acc + 16384;
        float* cs1  = rs1 + 4096;
        float* rs2  = cs1 + 4096;
        float* cs2  = rs2 + 4096;
        float* mr1  = cs2 + 4096;
        float* mc1  = mr1 + 4096;
        float* mr2  = mc1 + 4096;
        float* mc2  = mr2 + 4096;
        float* wsum = mc2 + 4096;
        float* wcnt = wsum + 4096;

        prep<<<dim3(4096), dim3(256), 0, stream>>>(z_mp1, z_sc1, z_mp2, z_sc2, W1, W2,
                                                   Zall, W1b, W2b, acc);
        gemm_bt<0><<<dim3(8, 128), dim3(256), 0, stream>>>(Zall, W1b, 16384, 1024, 1024,
            b1, Hall, nullptr, nullptr, nullptr, nullptr, nullptr);
        gemm_bt<1><<<dim3(8, 128), dim3(256), 0, stream>>>(Hall, W2b, 16384, 1024, 1024,
            b2, Pall, nsq, nullptr, nullptr, nullptr, nullptr);
        gemm_bt<2><<<dim3(32, 32), dim3(256), 0, stream>>>(Pall, Pall + 4194304, 4096, 4096, 1024,
            nullptr, Sbf, nullptr, nsq, nsq + 4096, rs1, cs1);
        pos_row<<<dim3(4096), dim3(256), 0, stream>>>(pos1, Sbf, mr1, mc1);
        gemm_bt<2><<<dim3(32, 32), dim3(256), 0, stream>>>(Pall + 8388608, Pall + 12582912, 4096, 4096, 1024,
            nullptr, Sbf, nullptr, nsq + 8192, nsq + 12288, rs2, cs2);
        pos_row<<<dim3(4096), dim3(256), 0, stream>>>(pos2, Sbf, mr2, mc2);
        combine2_bf16<<<dim3(8192), dim3(256), 0, stream>>>(z_mp1, z_sc1, z_mp2, z_sc2, gamma,
                                                            Z1b, Z2b, 1048576);
        gemm_bt<3><<<dim3(32, 32), dim3(256), 0, stream>>>(Z1b, Z2b, 4096, 4096, 1024,
            nullptr, Sbf, nullptr, nullptr, nullptr, nullptr, nullptr);
        md_row<<<dim3(4096), dim3(256), 0, stream>>>(mdm, Sbf, wsum, wcnt);
        finalize<<<dim3(1), dim3(256), 0, stream>>>(rs1, cs1, mr1, mc1, rs2, cs2, mr2, mc2,
                                                    wsum, wcnt, (unsigned int*)d_out);
    } else {
        // ---- split fallback (peak ~52.4 MB) ----
        unsigned short* Pv1 = (unsigned short*)(ws + (size_t)(4u << 20));
        unsigned short* Pv2 = (unsigned short*)(ws + (size_t)(20u << 20));
        unsigned short* Sbf = (unsigned short*)(ws + (size_t)(4u << 20));
        unsigned short* HBf = (unsigned short*)(ws + (size_t)(36u << 20));
        unsigned short* Z1b = (unsigned short*)(ws + (size_t)(36u << 20));
        unsigned short* Z2b = (unsigned short*)(ws + (size_t)(44u << 20));
        float* acc = (float*)(ws + (size_t)(52u << 20));
        float* nsq  = acc;            // 16384: [v1 mp|sc | v2 mp|sc]
        float* rs1  = acc + 16384;
        float* cs1  = rs1 + 4096;
        float* rs2  = cs1 + 4096;
        float* cs2  = rs2 + 4096;
        float* mr1  = cs2 + 4096;
        float* mc1  = mr1 + 4096;
        float* mr2  = mc1 + 4096;
        float* mc2  = mr2 + 4096;
        float* wsum = mc2 + 4096;
        float* wcnt = wsum + 4096;

        prep<<<dim3(4096), dim3(256), 0, stream>>>(z_mp1, z_sc1, z_mp2, z_sc2, W1, W2,
                                                   Zall, W1b, W2b, acc);
        gemm_bt<0><<<dim3(8, 64), dim3(256), 0, stream>>>(Zall, W1b, 8192, 1024, 1024,
            b1, HBf, nullptr, nullptr, nullptr, nullptr, nullptr);
        gemm_bt<1><<<dim3(8, 64), dim3(256), 0, stream>>>(HBf, W2b, 8192, 1024, 1024,
            b2, Pv1, nsq, nullptr, nullptr, nullptr, nullptr);
        gemm_bt<2><<<dim3(32, 32), dim3(256), 0, stream>>>(Pv1, Pv1 + 4194304, 4096, 4096, 1024,
            nullptr, Sbf, nullptr, nsq, nsq + 4096, rs1, cs1);
        pos_row<<<dim3(4096), dim3(256), 0, stream>>>(pos1, Sbf, mr1, mc1);
        gemm_bt<0><<<dim3(8, 64), dim3(256), 0, stream>>>(Zall + 8388608, W1b, 8192, 1024, 1024,
            b1, HBf, nullptr, nullptr, nullptr, nullptr, nullptr);
        gemm_bt<1><<<dim3(8, 64), dim3(256), 0, stream>>>(HBf, W2b, 8192, 1024, 1024,
            b2, Pv2, nsq + 8192, nullptr, nullptr, nullptr, nullptr);
        gemm_bt<2><<<dim3(32, 32), dim3(256), 0, stream>>>(Pv2, Pv2 + 4194304, 4096, 4096, 1024,
            nullptr, Sbf, nullptr, nsq + 8192, nsq + 12288, rs2, cs2);
        pos_row<<<dim3(4096), dim3(256), 0, stream>>>(pos2, Sbf, mr2, mc2);
        combine2_bf16<<<dim3(8192), dim3(256), 0, stream>>>(z_mp1, z_sc1, z_mp2, z_sc2, gamma,
                                                            Z1b, Z2b, 1048576);
        gemm_bt<3><<<dim3(32, 32), dim3(256), 0, stream>>>(Z1b, Z2b, 4096, 4096, 1024,
            nullptr, Sbf, nullptr, nullptr, nullptr, nullptr, nullptr);
        md_row<<<dim3(4096), dim3(256), 0, stream>>>(mdm, Sbf, wsum, wcnt);
        finalize<<<dim3(1), dim3(256), 0, stream>>>(rs1, cs1, mr1, mc1, rs2, cs2, mr2, mc2,
                                                    wsum, wcnt, (unsigned int*)d_out);
    }
}